// Round 8
// baseline (363.616 us; speedup 1.0000x reference)
//
#include <hip/hip_runtime.h>
#include <hip/hip_bf16.h>
#include <math.h>

#define B_    16
#define P_    25
#define D_SL_ 32
#define H_    320
#define W_    320
#define BP    400
#define KPIX  4096
#define FOUT  1280
#define HID   128
#define NG    3

#define M_PAD    512
#define KSPL     8
#define CH_STEPS 16          // 32-wide k-steps per k-chunk (512 k per chunk)
#define NBLK     512         // persistent grid; co-residency proven via launch_bounds(256,2)

typedef __attribute__((ext_vector_type(8))) short  bf16x8;
typedef __attribute__((ext_vector_type(8))) ushort u16x8;
typedef __attribute__((ext_vector_type(4))) float  f32x4;
typedef __attribute__((ext_vector_type(4))) unsigned int u32x4;
typedef unsigned long long ull;

// ws byte offsets
#define OFF_APH  0ull
#define OFF_APL  4194304ull
#define OFF_WPH  8388608ull
#define OFF_WPL  18874368ull
#define OFF_PART 29360128ull     // 8*400*1280*4 = 16.4MB -> ends ~45.7MB
#define OFF_BAR  67108864ull     // barrier counter (zeroed per launch)

__device__ inline void split_bf16(float x, ushort& hi, ushort& lo) {
    __hip_bfloat16 h = __float2bfloat16(x);
    float hf = __bfloat162float(h);
    __hip_bfloat16 l = __float2bfloat16(x - hf);
    hi = *(ushort*)&h;
    lo = *(ushort*)&l;
}

// grid-wide barrier: all NBLK blocks resident (see launch_bounds proof).
__device__ inline void gbar(unsigned* ctr, unsigned target) {
    __threadfence();                 // release my writes (wbL2)
    __syncthreads();
    if (threadIdx.x == 0) {
        atomicAdd(ctr, 1u);          // device scope by default
        while (__hip_atomic_load(ctr, __ATOMIC_RELAXED, __HIP_MEMORY_SCOPE_AGENT) < target)
            __builtin_amdgcn_s_sleep(2);
    }
    __syncthreads();
    __threadfence();                 // acquire: invalidate caches before reading peers' data
}

__global__ __launch_bounds__(256, 2) void mega(
    const float* __restrict__ images,
    const float* __restrict__ z_pred,
    const float* __restrict__ xy_pred,
    const int*   __restrict__ grade,
    const float* __restrict__ Wf,
    const float* __restrict__ bfeat,
    const float* __restrict__ W1, const float* __restrict__ b1,
    const float* __restrict__ W2, const float* __restrict__ b2,
    ushort* __restrict__ APH, ushort* __restrict__ APL,
    ushort* __restrict__ WPH, ushort* __restrict__ WPL,
    float* __restrict__ part,
    float* __restrict__ probs, float* out0, unsigned* bar)
{
    __shared__ __align__(16) unsigned char smem[40960];
    int t = threadIdx.x;
    int bid = blockIdx.x;

    // =================== P0: crops -> A panels  +  Wsum -> B panels ===================
    for (int u = bid; u < 1152; u += NBLK) {
        __syncthreads();
        if (u < 512) {
            // ---- crop unit (r4-proven) ----
            float (*S)[65] = (float(*)[65])smem;
            int pt = u;
            if (pt >= BP) {
                u16x8 z8 = (u16x8)0;
                #pragma unroll
                for (int i = 0; i < 2; ++i) {
                    int tau = t + i * 256;
                    int step = tau >> 2, q = tau & 3;
                    *(u16x8*)(APH + ((size_t)step * M_PAD + pt) * 32 + q * 8) = z8;
                    *(u16x8*)(APL + ((size_t)step * M_PAD + pt) * 32 + q * 8) = z8;
                }
                continue;
            }
            int b = pt / P_;
            int z = (int)rintf(z_pred[pt] - 1.0f);
            z = min(max(z, 0), D_SL_ - 1);
            int x = (int)rintf(4.0f * xy_pred[pt * 2 + 0]);
            int y = (int)rintf(4.0f * xy_pred[pt * 2 + 1]);
            x = min(max(x, 0), W_ - 1);
            y = min(max(y, 0), H_ - 1);
            const float* img = images + (size_t)(b * D_SL_ + z) * (H_ * W_);

            #pragma unroll
            for (int i = 0; i < 16; ++i) {
                int idx = t + i * 256;
                int r = idx >> 6, c = idx & 63;
                int iy = y - 32 + r, ix = x - 32 + c;
                float v = 0.0f;
                if ((unsigned)iy < (unsigned)H_ && (unsigned)ix < (unsigned)W_)
                    v = img[iy * W_ + ix];
                S[r][c] = v;
            }
            __syncthreads();

            #pragma unroll
            for (int i = 0; i < 2; ++i) {
                int tau = t + i * 256;
                int step = tau >> 2, q = tau & 3;
                int r = step >> 1, cb = (step & 1) * 32 + q * 8;
                u16x8 vh, vl;
                #pragma unroll
                for (int e = 0; e < 8; ++e) {
                    ushort hi, lo;
                    split_bf16(S[r][cb + e], hi, lo);
                    vh[e] = hi; vl[e] = lo;
                }
                *(u16x8*)(APH + ((size_t)step * M_PAD + pt) * 32 + q * 8) = vh;
                *(u16x8*)(APL + ((size_t)step * M_PAD + pt) * 32 + q * 8) = vl;
            }
        } else {
            // ---- W-prep unit (r5-proven) ----
            float (*S)[68] = (float(*)[68])smem;
            int wb = u - 512;                // 0..639
            int k0 = (wb & 31) * 128;
            int n0w = (wb >> 5) * 64;
            #pragma unroll
            for (int p = 0; p < 8; ++p) {
                int kl = p * 16 + (t >> 4);
                int nq = (t & 15) * 4;
                const float* base = Wf + (size_t)(k0 + kl) * FOUT + n0w + nq;
                float4 a = *(const float4*)base;
                float4 b = *(const float4*)(base + (size_t)KPIX * FOUT);
                float4 c = *(const float4*)(base + (size_t)2 * KPIX * FOUT);
                *(float4*)&S[kl][nq] = make_float4(a.x + b.x + c.x, a.y + b.y + c.y,
                                                   a.z + b.z + c.z, a.w + b.w + c.w);
            }
            __syncthreads();
            int stepl = t >> 6;
            int nl = t & 63;
            int gstep = (wb & 31) * 4 + stepl;
            ushort hi[32], lo[32];
            #pragma unroll
            for (int j = 0; j < 32; ++j) {
                float v = S[stepl * 32 + j][nl];
                split_bf16(v, hi[j], lo[j]);
            }
            ushort* oh = WPH + ((size_t)gstep * FOUT + n0w + nl) * 32;
            ushort* ol = WPL + ((size_t)gstep * FOUT + n0w + nl) * 32;
            #pragma unroll
            for (int q = 0; q < 4; ++q) {
                u16x8 vh, vl;
                #pragma unroll
                for (int e = 0; e < 8; ++e) { vh[e] = hi[q * 8 + e]; vl[e] = lo[q * 8 + e]; }
                *(u16x8*)(oh + q * 8) = vh;
                *(u16x8*)(ol + q * 8) = vl;
            }
        }
    }

    gbar(bar, NBLK);

    // =================== P1: MFMA GEMM (128M x 64N x 512K units) ===================
    // unit u: kz = u&7 (== bid&7 == XCD -> A k-chunk L2-pinned), 80 m/n tiles.
    for (int u = bid; u < 640; u += NBLK) {
        ushort* Atile = (ushort*)smem;             // 128 rows x 128B = 16KB
        ushort* Btile = (ushort*)smem + 128 * 64;  // 64 rows x 128B = 8KB
        int kz = u & 7;
        int rr2 = u >> 3;                          // 0..79
        int n0 = (rr2 % 20) * 64;
        int m0 = (rr2 / 20) * 128;
        int stepbase = kz * CH_STEPS;

        int w = t >> 6, l = t & 63;
        int wm = w & 1, wn = w >> 1;
        int l16 = l & 15, kg = l >> 4;

        f32x4 acc[4][2];
        #pragma unroll
        for (int i = 0; i < 4; ++i)
            #pragma unroll
            for (int j = 0; j < 2; ++j) acc[i][j] = (f32x4){0.f, 0.f, 0.f, 0.f};

        int tr = t >> 1, half = t & 1, hb = half * 8, rm = tr & 15;
        int trB = (t >> 1) & 63, rmB = trB & 15;

        u32x4 pa[4], pb[4];

#define LOADS(s_)                                                                    \
        {                                                                            \
            const ushort* asrc = (half ? APL : APH)                                  \
                + ((size_t)(stepbase + (s_)) * M_PAD + m0 + tr) * 32;                \
            pa[0] = ((const u32x4*)asrc)[0]; pa[1] = ((const u32x4*)asrc)[1];        \
            pa[2] = ((const u32x4*)asrc)[2]; pa[3] = ((const u32x4*)asrc)[3];        \
            if (t < 128) {                                                           \
                const ushort* bsrc = (half ? WPL : WPH)                              \
                    + ((size_t)(stepbase + (s_)) * FOUT + n0 + trB) * 32;            \
                pb[0] = ((const u32x4*)bsrc)[0]; pb[1] = ((const u32x4*)bsrc)[1];    \
                pb[2] = ((const u32x4*)bsrc)[2]; pb[3] = ((const u32x4*)bsrc)[3];    \
            }                                                                        \
        }

        LOADS(0);
        for (int s = 0; s < CH_STEPS; ++s) {
            __syncthreads();
            {
                ushort* arow = &Atile[tr * 64];
                #pragma unroll
                for (int q = 0; q < 4; ++q) {
                    #pragma unroll
                    for (int h = 0; h < 2; ++h) {
                        int j = q * 2 + h;
                        *(ull*)&arow[((hb + j) ^ rm) * 4] = ((const ull*)&pa[q])[h];
                    }
                }
                if (t < 128) {
                    ushort* brow = &Btile[trB * 64];
                    #pragma unroll
                    for (int q = 0; q < 4; ++q) {
                        #pragma unroll
                        for (int h = 0; h < 2; ++h) {
                            int j = q * 2 + h;
                            *(ull*)&brow[((hb + j) ^ rmB) * 4] = ((const ull*)&pb[q])[h];
                        }
                    }
                }
            }
            __syncthreads();
            if (s + 1 < CH_STEPS) LOADS(s + 1);

            union FragU { ull q[2]; bf16x8 v; };
            bf16x8 ah[4], al[4], bh[2], bl[2];
            #pragma unroll
            for (int mi = 0; mi < 4; ++mi) {
                int r = wm * 64 + mi * 16 + l16;
                const ushort* rowp = &Atile[r * 64];
                FragU fh, fl;
                fh.q[0] = *(const ull*)&rowp[(((2 * kg) ^ l16)) * 4];
                fh.q[1] = *(const ull*)&rowp[(((2 * kg + 1) ^ l16)) * 4];
                fl.q[0] = *(const ull*)&rowp[(((8 + 2 * kg) ^ l16)) * 4];
                fl.q[1] = *(const ull*)&rowp[(((9 + 2 * kg) ^ l16)) * 4];
                ah[mi] = fh.v; al[mi] = fl.v;
            }
            #pragma unroll
            for (int ni = 0; ni < 2; ++ni) {
                int r = wn * 32 + ni * 16 + l16;
                const ushort* rowp = &Btile[r * 64];
                FragU fh, fl;
                fh.q[0] = *(const ull*)&rowp[(((2 * kg) ^ l16)) * 4];
                fh.q[1] = *(const ull*)&rowp[(((2 * kg + 1) ^ l16)) * 4];
                fl.q[0] = *(const ull*)&rowp[(((8 + 2 * kg) ^ l16)) * 4];
                fl.q[1] = *(const ull*)&rowp[(((9 + 2 * kg) ^ l16)) * 4];
                bh[ni] = fh.v; bl[ni] = fl.v;
            }
            #pragma unroll
            for (int mi = 0; mi < 4; ++mi)
                #pragma unroll
                for (int ni = 0; ni < 2; ++ni) {
                    acc[mi][ni] = __builtin_amdgcn_mfma_f32_16x16x32_bf16(ah[mi], bh[ni], acc[mi][ni], 0, 0, 0);
                    acc[mi][ni] = __builtin_amdgcn_mfma_f32_16x16x32_bf16(ah[mi], bl[ni], acc[mi][ni], 0, 0, 0);
                    acc[mi][ni] = __builtin_amdgcn_mfma_f32_16x16x32_bf16(al[mi], bh[ni], acc[mi][ni], 0, 0, 0);
                }
        }
#undef LOADS

        #pragma unroll
        for (int mi = 0; mi < 4; ++mi)
            #pragma unroll
            for (int ni = 0; ni < 2; ++ni)
                #pragma unroll
                for (int r = 0; r < 4; ++r) {
                    int m = m0 + wm * 64 + mi * 16 + kg * 4 + r;
                    if (m < BP) {
                        int n = n0 + wn * 32 + ni * 16 + l16;
                        part[((size_t)kz * BP + m) * FOUT + n] = acc[mi][ni][r];
                    }
                }
        __syncthreads();
    }

    gbar(bar, 2 * NBLK);

    // =================== P2: MLP + softmax + loss (200 units x 2 rows) ===================
    float* sf   = (float*)smem;               // [2][1280]
    float* sh   = (float*)(smem + 10240);     // [2][128]
    float* sl   = (float*)(smem + 11264);     // [2][3]
    float* sden = (float*)(smem + 11296);     // [256]

    float dwt = 0.0f;
    for (int p = t; p < BP; p += 256) {
        int g = grade[p];
        dwt += (g == 0) ? 1.0f : (g == 1 ? 2.0f : 4.0f);
    }
    sden[t] = dwt;
    __syncthreads();
    for (int s = 128; s > 0; s >>= 1) {
        if (t < s) sden[t] += sden[t + s];
        __syncthreads();
    }
    float den = sden[0];
    __syncthreads();

    for (int u = bid; u < 200; u += NBLK) {
        int r0 = u * 2;
        for (int i = t; i < 2 * FOUT; i += 256) {
            int r = i / FOUT, c = i - r * FOUT;
            size_t base = (size_t)(r0 + r) * FOUT + c;
            float v = bfeat[c];
            #pragma unroll
            for (int kzi = 0; kzi < KSPL; ++kzi)
                v += part[(size_t)kzi * BP * FOUT + base];
            sf[r * FOUT + c] = v;
        }
        __syncthreads();
        {
            int rid = t >> 7, j = t & 127;
            float a = b1[j];
            const float* sp = &sf[rid * FOUT];
            #pragma unroll 8
            for (int k = 0; k < FOUT; ++k)
                a = fmaf(sp[k], W1[(size_t)k * HID + j], a);
            sh[rid * HID + j] = fmaxf(a, 0.0f);
        }
        __syncthreads();
        if (t < 6) {
            int rr = t / 3, c = t - rr * 3;
            float a = b2[c];
            #pragma unroll 16
            for (int k = 0; k < HID; ++k) a = fmaf(sh[rr * HID + k], W2[k * NG + c], a);
            sl[rr * NG + c] = a;
        }
        __syncthreads();
        if (t < 2) {
            float l0 = sl[t * NG + 0], l1 = sl[t * NG + 1], l2 = sl[t * NG + 2];
            float m = fmaxf(l0, fmaxf(l1, l2));
            float e0 = expf(l0 - m), e1 = expf(l1 - m), e2 = expf(l2 - m);
            float inv = 1.0f / (e0 + e1 + e2);
            int row = r0 + t;
            probs[row * NG + 0] = e0 * inv;
            probs[row * NG + 1] = e1 * inv;
            probs[row * NG + 2] = e2 * inv;

            int g = grade[row];
            float lv = (g == 0) ? l0 : (g == 1 ? l1 : l2);
            lv = fminf(fmaxf(lv, 1e-5f), 1.0f - 1e-5f);
            float wt = (g == 0) ? 1.0f : (g == 1 ? 2.0f : 4.0f);
            atomicAdd(out0, -(wt * logf(lv)) / den);
        }
        __syncthreads();
    }
}

// ---------------- launch ----------------
extern "C" void kernel_launch(void* const* d_in, const int* in_sizes, int n_in,
                              void* d_out, int out_size, void* d_ws, size_t ws_size,
                              hipStream_t stream) {
    const float* images  = (const float*)d_in[0];
    const float* z_pred  = (const float*)d_in[1];
    const float* xy_pred = (const float*)d_in[2];
    const int*   grade   = (const int*)d_in[3];
    const float* W_feat  = (const float*)d_in[4];
    const float* b_feat  = (const float*)d_in[5];
    const float* W1      = (const float*)d_in[6];
    const float* b1      = (const float*)d_in[7];
    const float* W2      = (const float*)d_in[8];
    const float* b2      = (const float*)d_in[9];

    float* out = (float*)d_out;
    char* w = (char*)d_ws;
    ushort* APH = (ushort*)(w + OFF_APH);
    ushort* APL = (ushort*)(w + OFF_APL);
    ushort* WPH = (ushort*)(w + OFF_WPH);
    ushort* WPL = (ushort*)(w + OFF_WPL);
    float*  part = (float*)(w + OFF_PART);
    unsigned* bar = (unsigned*)(w + OFF_BAR);

    hipMemsetAsync(bar, 0, 64, stream);       // barrier counter
    hipMemsetAsync(out, 0, 4, stream);        // loss accumulator
    mega<<<NBLK, 256, 0, stream>>>(images, z_pred, xy_pred, grade, W_feat, b_feat,
                                   W1, b1, W2, b2, APH, APL, WPH, WPL, part,
                                   out + 1, out, bar);
}

// Round 9
// 72.947 us; speedup vs baseline: 4.9847x; 4.9847x over previous
//
#include <hip/hip_runtime.h>
#include <hip/hip_bf16.h>
#include <math.h>

#define B_    16
#define P_    25
#define D_SL_ 32
#define H_    320
#define W_    320
#define BP    400
#define KPIX  4096
#define FOUT  1280
#define HID   128
#define NG    3

// gemm geometry
#define M_PAD    512         // 4 m-tiles of 128
#define KSPL     8           // k-chunks
#define CH_STEPS 16          // 32-wide k-steps per chunk

#define CROP_BLOCKS 512      // fused_prep: blocks [0,512) crops, [512,1152) prep_w

typedef __attribute__((ext_vector_type(8))) short  bf16x8;
typedef __attribute__((ext_vector_type(8))) ushort u16x8;
typedef __attribute__((ext_vector_type(4))) float  f32x4;
typedef __attribute__((ext_vector_type(4))) unsigned int u32x4;
typedef unsigned long long ull;

// ws byte offsets
#define OFF_APH  0ull
#define OFF_APL  4194304ull      // 128*512*32*2
#define OFF_WPH  8388608ull
#define OFF_WPL  18874368ull     // + 128*1280*32*2
#define OFF_PART 29360128ull

__device__ inline void split_bf16(float x, ushort& hi, ushort& lo) {
    __hip_bfloat16 h = __float2bfloat16(x);
    float hf = __bfloat162float(h);
    __hip_bfloat16 l = __float2bfloat16(x - hf);
    hi = *(ushort*)&h;
    lo = *(ushort*)&l;
}

// ---------------- fused prep: crops->panels  +  Wsum->panels (r5-proven) --------
__global__ __launch_bounds__(256) void fused_prep(
    const float* __restrict__ images,
    const float* __restrict__ z_pred,
    const float* __restrict__ xy_pred,
    const float* __restrict__ Wf,
    ushort* __restrict__ APH, ushort* __restrict__ APL,
    ushort* __restrict__ WPH, ushort* __restrict__ WPL)
{
    __shared__ float S[128][68];
    int t = threadIdx.x;

    if (blockIdx.x < CROP_BLOCKS) {
        int pt = blockIdx.x;
        if (pt >= BP) {
            u16x8 z8 = (u16x8)0;
            #pragma unroll
            for (int i = 0; i < 2; ++i) {
                int tau = t + i * 256;
                int step = tau >> 2, q = tau & 3;
                *(u16x8*)(APH + ((size_t)step * M_PAD + pt) * 32 + q * 8) = z8;
                *(u16x8*)(APL + ((size_t)step * M_PAD + pt) * 32 + q * 8) = z8;
            }
            return;
        }
        int b = pt / P_;
        int z = (int)rintf(z_pred[pt] - 1.0f);
        z = min(max(z, 0), D_SL_ - 1);
        int x = (int)rintf(4.0f * xy_pred[pt * 2 + 0]);
        int y = (int)rintf(4.0f * xy_pred[pt * 2 + 1]);
        x = min(max(x, 0), W_ - 1);
        y = min(max(y, 0), H_ - 1);
        const float* img = images + (size_t)(b * D_SL_ + z) * (H_ * W_);

        #pragma unroll
        for (int i = 0; i < 16; ++i) {
            int idx = t + i * 256;
            int r = idx >> 6, c = idx & 63;
            int iy = y - 32 + r, ix = x - 32 + c;
            float v = 0.0f;
            if ((unsigned)iy < (unsigned)H_ && (unsigned)ix < (unsigned)W_)
                v = img[iy * W_ + ix];
            S[r][c] = v;
        }
        __syncthreads();

        #pragma unroll
        for (int i = 0; i < 2; ++i) {
            int tau = t + i * 256;
            int step = tau >> 2, q = tau & 3;
            int r = step >> 1, cb = (step & 1) * 32 + q * 8;
            u16x8 vh, vl;
            #pragma unroll
            for (int e = 0; e < 8; ++e) {
                ushort hi, lo;
                split_bf16(S[r][cb + e], hi, lo);
                vh[e] = hi; vl[e] = lo;
            }
            *(u16x8*)(APH + ((size_t)step * M_PAD + pt) * 32 + q * 8) = vh;
            *(u16x8*)(APL + ((size_t)step * M_PAD + pt) * 32 + q * 8) = vl;
        }
        return;
    }

    int wb = blockIdx.x - CROP_BLOCKS;   // 0..639
    int k0 = (wb & 31) * 128;
    int n0 = (wb >> 5) * 64;
    #pragma unroll
    for (int p = 0; p < 8; ++p) {
        int kl = p * 16 + (t >> 4);
        int nq = (t & 15) * 4;
        const float* base = Wf + (size_t)(k0 + kl) * FOUT + n0 + nq;
        float4 a = *(const float4*)base;
        float4 b = *(const float4*)(base + (size_t)KPIX * FOUT);
        float4 c = *(const float4*)(base + (size_t)2 * KPIX * FOUT);
        *(float4*)&S[kl][nq] = make_float4(a.x + b.x + c.x, a.y + b.y + c.y,
                                           a.z + b.z + c.z, a.w + b.w + c.w);
    }
    __syncthreads();
    int stepl = t >> 6;
    int nl = t & 63;
    int gstep = (wb & 31) * 4 + stepl;
    ushort hi[32], lo[32];
    #pragma unroll
    for (int j = 0; j < 32; ++j) {
        float v = S[stepl * 32 + j][nl];
        split_bf16(v, hi[j], lo[j]);
    }
    ushort* oh = WPH + ((size_t)gstep * FOUT + n0 + nl) * 32;
    ushort* ol = WPL + ((size_t)gstep * FOUT + n0 + nl) * 32;
    #pragma unroll
    for (int q = 0; q < 4; ++q) {
        u16x8 vh, vl;
        #pragma unroll
        for (int e = 0; e < 8; ++e) { vh[e] = hi[q * 8 + e]; vl[e] = lo[q * 8 + e]; }
        *(u16x8*)(oh + q * 8) = vh;
        *(u16x8*)(ol + q * 8) = vl;
    }
}

// ---------------- MFMA GEMM (r5-proven: 1D grid, kz->XCD swizzle) ----------------
__global__ __launch_bounds__(256) void gemm_mfma(
    const ushort* __restrict__ APH, const ushort* __restrict__ APL,
    const ushort* __restrict__ WPH, const ushort* __restrict__ WPL,
    float* __restrict__ part, float* __restrict__ out0)
{
    __shared__ ushort Atile[128 * 64];
    __shared__ ushort Btile[128 * 64];

    int t = threadIdx.x;
    int id = blockIdx.x;
    int kz = id & 7;
    int rr_ = id >> 3;               // 0..39
    int n0 = (rr_ % 10) * 128;
    int m0 = (rr_ / 10) * 128;
    int stepbase = kz * CH_STEPS;

    if (id == 0 && t == 0) out0[0] = 0.0f;

    int w = t >> 6, l = t & 63;
    int wm = w & 1, wn = w >> 1;
    int l16 = l & 15, kg = l >> 4;

    f32x4 acc[4][4];
    #pragma unroll
    for (int i = 0; i < 4; ++i)
        #pragma unroll
        for (int j = 0; j < 4; ++j) acc[i][j] = (f32x4){0.f, 0.f, 0.f, 0.f};

    int tr = t >> 1;
    int hb = (t & 1) * 8;
    int rm = tr & 15;

    u32x4 pa[4], pb[4];

#define LOADS(s_)                                                                   \
    {                                                                               \
        const ushort* asrc = ((t & 1) ? APL : APH)                                  \
            + ((size_t)(stepbase + (s_)) * M_PAD + m0 + tr) * 32;                   \
        const ushort* bsrc = ((t & 1) ? WPL : WPH)                                  \
            + ((size_t)(stepbase + (s_)) * FOUT + n0 + tr) * 32;                    \
        pa[0] = ((const u32x4*)asrc)[0]; pa[1] = ((const u32x4*)asrc)[1];           \
        pa[2] = ((const u32x4*)asrc)[2]; pa[3] = ((const u32x4*)asrc)[3];           \
        pb[0] = ((const u32x4*)bsrc)[0]; pb[1] = ((const u32x4*)bsrc)[1];           \
        pb[2] = ((const u32x4*)bsrc)[2]; pb[3] = ((const u32x4*)bsrc)[3];           \
    }

    LOADS(0);
    for (int s = 0; s < CH_STEPS; ++s) {
        __syncthreads();
        {
            ushort* arow = &Atile[tr * 64];
            ushort* brow = &Btile[tr * 64];
            #pragma unroll
            for (int q = 0; q < 4; ++q) {
                #pragma unroll
                for (int h = 0; h < 2; ++h) {
                    int j = q * 2 + h;
                    int u = (hb + j) ^ rm;
                    *(ull*)&arow[u * 4] = ((const ull*)&pa[q])[h];
                    *(ull*)&brow[u * 4] = ((const ull*)&pb[q])[h];
                }
            }
        }
        __syncthreads();
        if (s + 1 < CH_STEPS) LOADS(s + 1);

        union FragU { ull q[2]; bf16x8 v; };
        bf16x8 ah[4], al[4], bh[4], bl[4];
        #pragma unroll
        for (int mi = 0; mi < 4; ++mi) {
            int r = wm * 64 + mi * 16 + l16;
            const ushort* rowp = &Atile[r * 64];
            FragU fh, fl;
            fh.q[0] = *(const ull*)&rowp[(((2 * kg) ^ l16)) * 4];
            fh.q[1] = *(const ull*)&rowp[(((2 * kg + 1) ^ l16)) * 4];
            fl.q[0] = *(const ull*)&rowp[(((8 + 2 * kg) ^ l16)) * 4];
            fl.q[1] = *(const ull*)&rowp[(((9 + 2 * kg) ^ l16)) * 4];
            ah[mi] = fh.v; al[mi] = fl.v;
        }
        #pragma unroll
        for (int ni = 0; ni < 4; ++ni) {
            int r = wn * 64 + ni * 16 + l16;
            const ushort* rowp = &Btile[r * 64];
            FragU fh, fl;
            fh.q[0] = *(const ull*)&rowp[(((2 * kg) ^ l16)) * 4];
            fh.q[1] = *(const ull*)&rowp[(((2 * kg + 1) ^ l16)) * 4];
            fl.q[0] = *(const ull*)&rowp[(((8 + 2 * kg) ^ l16)) * 4];
            fl.q[1] = *(const ull*)&rowp[(((9 + 2 * kg) ^ l16)) * 4];
            bh[ni] = fh.v; bl[ni] = fl.v;
        }
        #pragma unroll
        for (int mi = 0; mi < 4; ++mi)
            #pragma unroll
            for (int ni = 0; ni < 4; ++ni) {
                acc[mi][ni] = __builtin_amdgcn_mfma_f32_16x16x32_bf16(ah[mi], bh[ni], acc[mi][ni], 0, 0, 0);
                acc[mi][ni] = __builtin_amdgcn_mfma_f32_16x16x32_bf16(ah[mi], bl[ni], acc[mi][ni], 0, 0, 0);
                acc[mi][ni] = __builtin_amdgcn_mfma_f32_16x16x32_bf16(al[mi], bh[ni], acc[mi][ni], 0, 0, 0);
            }
    }
#undef LOADS

    #pragma unroll
    for (int mi = 0; mi < 4; ++mi)
        #pragma unroll
        for (int ni = 0; ni < 4; ++ni)
            #pragma unroll
            for (int r = 0; r < 4; ++r) {
                int m = m0 + wm * 64 + mi * 16 + kg * 4 + r;
                if (m < BP) {
                    int n = n0 + wn * 64 + ni * 16 + l16;
                    part[((size_t)kz * BP + m) * FOUT + n] = acc[mi][ni][r];
                }
            }
}

// ---------------- MLP + softmax + fused loss: 2 rows/block, 4-way K-split, 200 blocks ----
__global__ __launch_bounds__(512) void mlp2x_loss(
    const float* __restrict__ part,
    const float* __restrict__ bfeat,
    const float* __restrict__ W1, const float* __restrict__ b1,
    const float* __restrict__ W2, const float* __restrict__ b2,
    const int* __restrict__ grade,
    float* __restrict__ probs, float* __restrict__ out0)
{
    __shared__ float sf[2][FOUT];       // 10 KB
    __shared__ float shp[4][2][HID];    // 4 KB
    __shared__ float sh[2][HID];
    __shared__ float sl[2][NG];
    __shared__ float sden[512];
    int r0 = blockIdx.x * 2;            // 200 blocks
    int t = threadIdx.x;

    float dwt = 0.0f;
    if (t < BP) {
        int g = grade[t];
        dwt = (g == 0) ? 1.0f : (g == 1 ? 2.0f : 4.0f);
    }
    sden[t] = dwt;

    for (int i = t; i < 2 * FOUT; i += 512) {
        int r = i / FOUT, c = i - r * FOUT;
        size_t base = (size_t)(r0 + r) * FOUT + c;
        float v = bfeat[c];
        #pragma unroll
        for (int kzi = 0; kzi < KSPL; ++kzi)
            v += part[(size_t)kzi * BP * FOUT + base];
        sf[r][c] = v;
    }
    __syncthreads();
    for (int s = 256; s > 0; s >>= 1) {
        if (t < s) sden[t] += sden[t + s];
        __syncthreads();
    }
    float den = sden[0];

    {
        int kq = t >> 7, j = t & 127;   // kq: quarter of K (320 each)
        float a0 = (kq == 0) ? b1[j] : 0.0f, a1 = 0.0f;
        const float* wp = W1 + (size_t)(kq * 320) * HID + j;
        const float* s0 = &sf[0][kq * 320];
        const float* s1 = &sf[1][kq * 320];
        #pragma unroll 8
        for (int k = 0; k < 320; ++k) {
            float wv = wp[(size_t)k * HID];
            a0 = fmaf(s0[k], wv, a0);
            a1 = fmaf(s1[k], wv, a1);
        }
        shp[kq][0][j] = a0;
        shp[kq][1][j] = a1;
    }
    __syncthreads();
    if (t < 256) {
        int rr = t >> 7, j = t & 127;
        sh[rr][j] = fmaxf(shp[0][rr][j] + shp[1][rr][j] + shp[2][rr][j] + shp[3][rr][j], 0.0f);
    }
    __syncthreads();
    if (t < 6) {
        int rr = t / 3, c = t - rr * 3;
        float a = b2[c];
        #pragma unroll 16
        for (int k = 0; k < HID; ++k) a = fmaf(sh[rr][k], W2[k * NG + c], a);
        sl[rr][c] = a;
    }
    __syncthreads();
    if (t < 2) {
        float l0 = sl[t][0], l1 = sl[t][1], l2 = sl[t][2];
        float m = fmaxf(l0, fmaxf(l1, l2));
        float e0 = expf(l0 - m), e1 = expf(l1 - m), e2 = expf(l2 - m);
        float inv = 1.0f / (e0 + e1 + e2);
        int row = r0 + t;
        probs[row * NG + 0] = e0 * inv;
        probs[row * NG + 1] = e1 * inv;
        probs[row * NG + 2] = e2 * inv;

        int g = grade[row];
        float lv = (g == 0) ? l0 : (g == 1 ? l1 : l2);
        lv = fminf(fmaxf(lv, 1e-5f), 1.0f - 1e-5f);
        float wt = (g == 0) ? 1.0f : (g == 1 ? 2.0f : 4.0f);
        atomicAdd(out0, -(wt * logf(lv)) / den);
    }
}

// ---------------- launch ----------------
extern "C" void kernel_launch(void* const* d_in, const int* in_sizes, int n_in,
                              void* d_out, int out_size, void* d_ws, size_t ws_size,
                              hipStream_t stream) {
    const float* images  = (const float*)d_in[0];
    const float* z_pred  = (const float*)d_in[1];
    const float* xy_pred = (const float*)d_in[2];
    const int*   grade   = (const int*)d_in[3];
    const float* W_feat  = (const float*)d_in[4];
    const float* b_feat  = (const float*)d_in[5];
    const float* W1      = (const float*)d_in[6];
    const float* b1      = (const float*)d_in[7];
    const float* W2      = (const float*)d_in[8];
    const float* b2      = (const float*)d_in[9];

    float* out = (float*)d_out;
    char* w = (char*)d_ws;
    ushort* APH = (ushort*)(w + OFF_APH);
    ushort* APL = (ushort*)(w + OFF_APL);
    ushort* WPH = (ushort*)(w + OFF_WPH);
    ushort* WPL = (ushort*)(w + OFF_WPL);
    float*  part = (float*)(w + OFF_PART);

    fused_prep<<<CROP_BLOCKS + 640, 256, 0, stream>>>(images, z_pred, xy_pred, W_feat,
                                                      APH, APL, WPH, WPL);
    gemm_mfma<<<10 * 4 * KSPL, 256, 0, stream>>>(APH, APL, WPH, WPL, part, out);
    mlp2x_loss<<<BP / 2, 512, 0, stream>>>(part, b_feat, W1, b1, W2, b2, grade, out + 1, out);
}